// Round 14
// baseline (441.854 us; speedup 1.0000x reference)
//
#include <hip/hip_runtime.h>
#include <hip/hip_bf16.h>
#include <stdint.h>

typedef __attribute__((ext_vector_type(8))) short short8;
typedef __attribute__((ext_vector_type(4))) float f32x4;
typedef __attribute__((ext_vector_type(16))) float f32x16;
typedef __attribute__((ext_vector_type(2))) unsigned int uint2v;

__device__ __forceinline__ unsigned short f2bf(float f) {
  union { float f; unsigned int u; } v; v.f = f;
  unsigned int r = v.u + 0x7FFFu + ((v.u >> 16) & 1u);
  return (unsigned short)(r >> 16);
}

__device__ __forceinline__ unsigned int cvtpk(float lo, float hi) {
  unsigned int r;
  asm("v_cvt_pk_bf16_f32 %0, %1, %2" : "=v"(r) : "v"(lo), "v"(hi));
  return r;
}

#define GLOAD16(gsrc, ldst)                                                                  \
  __builtin_amdgcn_global_load_lds((const __attribute__((address_space(1))) void*)(gsrc),    \
                                   (__attribute__((address_space(3))) void*)(ldst), 16, 0, 0)

#define BAR() __builtin_amdgcn_s_barrier()
#define LGKMC(n) do { asm volatile("s_waitcnt lgkmcnt(" #n ")" ::: "memory"); \
                      __builtin_amdgcn_sched_barrier(0); } while (0)
#define LGKM0() LGKMC(0)
#define VMCNT0() asm volatile("s_waitcnt vmcnt(0)" ::: "memory")
#define VMCNT8() do { asm volatile("s_waitcnt vmcnt(8)" ::: "memory"); \
                      __builtin_amdgcn_sched_barrier(0); } while (0)
#define PRIO(x) __builtin_amdgcn_s_setprio(x)
#define MFMA32(d, a, b) d = __builtin_amdgcn_mfma_f32_32x32x16_bf16(a, b, d, 0, 0, 0)

// ---------------- cast x (fp32 -> bf16), 4 elems/thread ----------------
__global__ __launch_bounds__(256) void cast_bf16_kernel(const float* __restrict__ in,
                                                        unsigned short* __restrict__ out) {
  int i = blockIdx.x * 256 + threadIdx.x;
  float4 v = ((const float4*)in)[i];
  ushort4 o;
  o.x = f2bf(v.x); o.y = f2bf(v.y); o.z = f2bf(v.z); o.w = f2bf(v.w);
  ((ushort4*)out)[i] = o;
}

// ---------------- transpose + cast W: [K][N] fp32 -> [N][K] bf16 ----------------
__global__ __launch_bounds__(256) void transpose_cast_kernel(const float* __restrict__ W,
                                                             unsigned short* __restrict__ Wt,
                                                             int K, int N) {
  __shared__ float tile[32][33];
  int n0 = blockIdx.x * 32, k0 = blockIdx.y * 32;
  int tx = threadIdx.x, ty = threadIdx.y;
#pragma unroll
  for (int j = 0; j < 32; j += 8)
    tile[ty + j][tx] = W[(size_t)(k0 + ty + j) * N + n0 + tx];
  __syncthreads();
#pragma unroll
  for (int j = 0; j < 32; j += 8)
    Wt[(size_t)(n0 + ty + j) * K + k0 + tx] = f2bf(tile[tx][ty + j]);
}

// ---------------- 256x256 GEMM mainloop: 32x32x16 MFMA, clustered reads + counted lgkm ----------------
// Wave tile 128x64 = 4 m-subtiles x 2 n-subtiles of 32x32; acc[4][2] f32x16.
// Per K-tile: 24 ds_read_b128 (A 16, B 8) feed 32 MFMA (vs 64 at 16x16) -> -15% matrix-pipe cycles.
// Operand: lane reads 16B at row/col (base + l31), k-chunk (ks*2+hi), XOR-swizzle chunk^(l31&7).
__device__ __forceinline__ void stage_half(const unsigned short* __restrict__ gp, int K,
                                           int kt, int half, char* lds_mat, int tid) {
#pragma unroll
  for (int it = 0; it < 2; ++it) {
    int li = half * 1024 + it * 512 + tid;  // 16B-chunk index in 256x64 tile
    int r = li >> 3, c = li & 7;
    int cs = c ^ (r & 7);
    GLOAD16(gp + (size_t)r * K + kt * 64 + cs * 8, lds_mat + li * 16);
  }
}

__device__ __forceinline__ void gemm256_mainloop(const unsigned short* __restrict__ Ap,
                                                 const unsigned short* __restrict__ Bp,
                                                 int K, int tid, char* smem,
                                                 f32x16 acc[4][2]) {
  char* sa = smem;           // A: 2 bufs x 32768 B
  char* sb = smem + 65536;   // B: 2 bufs x 32768 B
  const int KT = K >> 6;     // 32

  int wid = tid >> 6, lane = tid & 63;
  int wr = wid >> 2, wc = wid & 3;
  int l31 = lane & 31, hi = lane >> 5;
  int swz7 = l31 & 7;

#define LDA(ab, ms, ks) \
  (*(const short8*)((const unsigned short*)(ab) + (size_t)((wr * 128 + (ms) * 32 + l31) * 64 + ((((ks) * 2 + hi) ^ swz7) * 8))))
#define LDB(bb, ns, ks) \
  (*(const short8*)((const unsigned short*)(bb) + (size_t)((wc * 64 + (ns) * 32 + l31) * 64 + ((((ks) * 2 + hi) ^ swz7) * 8))))

  // prologue: t0 fully (oldest 8 loads), then t1 fully (next 8, stay in flight)
  stage_half(Bp, K, 0, 0, sb, tid);
  stage_half(Bp, K, 0, 1, sb, tid);
  stage_half(Ap, K, 0, 0, sa, tid);
  stage_half(Ap, K, 0, 1, sa, tid);
  stage_half(Bp, K, 1, 0, sb + 32768, tid);
  stage_half(Bp, K, 1, 1, sb + 32768, tid);
  stage_half(Ap, K, 1, 0, sa + 32768, tid);
  stage_half(Ap, K, 1, 1, sa + 32768, tid);
  VMCNT8();  // t0's 8 loads complete; t1's 8 float
  BAR();

  for (int t = 0; t < KT; ++t) {
    int p = t & 1;
    const char* ab = sa + p * 32768;
    const char* bb = sb + p * 32768;
    int kt2 = (t + 2 < KT) ? t + 2 : KT - 1;

    short8 b0[4], b1[4], a01[2][4], a23[2][4];
    // ---- issue all 24 ds_reads in order: b0(4), a01(8), b1(4), a23(8) ----
#pragma unroll
    for (int ks = 0; ks < 4; ++ks) b0[ks] = LDB(bb, 0, ks);
#pragma unroll
    for (int ms = 0; ms < 2; ++ms)
#pragma unroll
      for (int ks = 0; ks < 4; ++ks) a01[ms][ks] = LDA(ab, ms, ks);
#pragma unroll
    for (int ks = 0; ks < 4; ++ks) b1[ks] = LDB(bb, 1, ks);
#pragma unroll
    for (int ms = 0; ms < 2; ++ms)
#pragma unroll
      for (int ks = 0; ks < 4; ++ks) a23[ms][ks] = LDA(ab, ms + 2, ks);

    // ---- Q1 = ms0-1 x ns0 (needs oldest 12) ----
    LGKMC(12);
    PRIO(1);
#pragma unroll
    for (int ks = 0; ks < 4; ++ks)
#pragma unroll
      for (int ms = 0; ms < 2; ++ms)
        MFMA32(acc[ms][0], a01[ms][ks], b0[ks]);
    PRIO(0);

    // ---- b1 done -> all B reads of tile t complete; BAR; stage B(t+2)->p ----
    LGKMC(8);
    BAR();
    stage_half(Bp, K, kt2, 0, sb + p * 32768, tid);
    stage_half(Bp, K, kt2, 1, sb + p * 32768, tid);

    // ---- Q2 = ms0-1 x ns1 ----
    PRIO(1);
#pragma unroll
    for (int ks = 0; ks < 4; ++ks)
#pragma unroll
      for (int ms = 0; ms < 2; ++ms)
        MFMA32(acc[ms][1], a01[ms][ks], b1[ks]);
    PRIO(0);

    // ---- a23 done -> Q3 = ms2-3 x ns1 ----
    LGKMC(0);
    PRIO(1);
#pragma unroll
    for (int ks = 0; ks < 4; ++ks)
#pragma unroll
      for (int ms = 0; ms < 2; ++ms)
        MFMA32(acc[ms + 2][1], a23[ms][ks], b1[ks]);
    PRIO(0);

    // ---- all A reads complete; BAR; stage A(t+2)->p; Q4 = ms2-3 x ns0 ----
    BAR();
    stage_half(Ap, K, kt2, 0, sa + p * 32768, tid);
    stage_half(Ap, K, kt2, 1, sa + p * 32768, tid);
    PRIO(1);
#pragma unroll
    for (int ks = 0; ks < 4; ++ks)
#pragma unroll
      for (int ms = 0; ms < 2; ++ms)
        MFMA32(acc[ms + 2][0], a23[ms][ks], b0[ks]);
    PRIO(0);
    VMCNT8();  // A(t+1),B(t+1) complete; A(t+2),B(t+2) (8 loads) float
    BAR();
  }
#undef LDA
#undef LDB
}

// ---------------- QKV GEMM 256^2: chunked XCD map; scatter q (pre-scaled) / k; v^T via LDS transpose ----------------
__global__ __launch_bounds__(512, 2) void gemm_qkv256_kernel(const unsigned short* __restrict__ A,
                                                             const unsigned short* __restrict__ Bt,
                                                             const float* __restrict__ bias,
                                                             unsigned short* __restrict__ qb,
                                                             unsigned short* __restrict__ kb,
                                                             unsigned short* __restrict__ vtb) {
  extern __shared__ char smem[];
  int wg = blockIdx.x;                 // 768 blocks
  int xcd = wg & 7, idx = wg >> 3;     // 96 per XCD
  int bn = xcd * 3 + idx % 3;          // bn-fast: 3 concurrent blocks share each A-panel in L2
  int bm = idx / 3;                    // 0..31
  int tid = threadIdx.x;

  f32x16 acc[4][2];
#pragma unroll
  for (int ms = 0; ms < 4; ++ms)
#pragma unroll
    for (int ns = 0; ns < 2; ++ns) acc[ms][ns] = (f32x16){};

  gemm256_mainloop(A + (size_t)bm * 256 * 2048, Bt + (size_t)bn * 256 * 2048, 2048, tid, smem, acc);

  const float QSCALE = (float)(0.08838834764831845 * 1.4426950408889634);  // D^-0.5 * log2(e)
  int wid = tid >> 6, lane = tid & 63;
  int wr = wid >> 2, wc = wid & 3;
  int l31 = lane & 31, hi = lane >> 5;

  if (bn >= 16) {
    // ---- v-block: transpose 256x256 tile via LDS, write [bh][d][t] coalesced ----
    VMCNT0();  // drain tail junk prefetches before reusing LDS
    BAR();
#pragma unroll
    for (int ns = 0; ns < 2; ++ns) {
      int cl = wc * 64 + ns * 32 + l31;
      float bv = bias[bn * 256 + cl];
#pragma unroll
      for (int ms = 0; ms < 4; ++ms) {
#pragma unroll
        for (int rq = 0; rq < 4; ++rq) {
          int rl = wr * 128 + ms * 32 + rq * 8 + 4 * hi;
          unsigned int w0 = cvtpk(acc[ms][ns][rq * 4 + 0] + bv, acc[ms][ns][rq * 4 + 1] + bv);
          unsigned int w1 = cvtpk(acc[ms][ns][rq * 4 + 2] + bv, acc[ms][ns][rq * 4 + 3] + bv);
          uint2v pk = {w0, w1};
          *(uint2v*)(smem + cl * 512 + ((rl * 2) ^ ((cl & 7) << 4))) = pk;
        }
      }
    }
    LGKM0();
    BAR();
    int t0_abs = bm * 256;
    int bq_ = t0_abs >> 11, t0 = t0_abs & 2047;
    int h0 = (bn * 256 - 4096) >> 7;  // first of 2 heads in this block
#pragma unroll
    for (int i = 0; i < 16; ++i) {
      int dloc = i * 16 + wid * 2 + hi;  // 0..255
      short8 vrow = *(const short8*)(smem + dloc * 512 + ((l31 * 16) ^ ((dloc & 7) << 4)));
      int bh_ = bq_ * 16 + h0 + (dloc >> 7);
      int d = dloc & 127;
      *(short8*)(vtb + ((size_t)bh_ * 128 + d) * 2048 + t0 + l31 * 8) = vrow;
    }
  } else {
    // ---- q/k block: direct scatter ----
#pragma unroll
    for (int ns = 0; ns < 2; ++ns) {
      int col = bn * 256 + wc * 64 + ns * 32 + l31;  // [0,4096)
      float bv = bias[col];
      int which = col >> 11;       // 0=q 1=k (block-uniform)
      int h = (col & 2047) >> 7;
      int d = col & 127;
#pragma unroll
      for (int ms = 0; ms < 4; ++ms) {
#pragma unroll
        for (int reg = 0; reg < 16; ++reg) {
          int row = bm * 256 + wr * 128 + ms * 32 + (reg & 3) + 8 * (reg >> 2) + 4 * hi;
          int b = row >> 11, t = row & 2047;
          float r = acc[ms][ns][reg] + bv;
          if (which == 0) r *= QSCALE;
          unsigned short val = f2bf(r);
          size_t bhi = (size_t)(b * 16 + h);
          if (which == 0) qb[(bhi * 2048 + t) * 128 + d] = val;
          else            kb[(bhi * 2048 + t) * 128 + d] = val;
        }
      }
    }
  }
}

// ---------------- Proj GEMM 256^2: fp32 output + bias ----------------
__global__ __launch_bounds__(512, 2) void gemm_proj256_kernel(const unsigned short* __restrict__ A,
                                                              const unsigned short* __restrict__ Bt,
                                                              const float* __restrict__ bias,
                                                              float* __restrict__ out) {
  extern __shared__ char smem[];
  int wg = blockIdx.x;
  int bm = wg >> 3, bn = wg & 7;  // one bn column per XCD; B-panel L2-resident
  int tid = threadIdx.x;

  f32x16 acc[4][2];
#pragma unroll
  for (int ms = 0; ms < 4; ++ms)
#pragma unroll
    for (int ns = 0; ns < 2; ++ns) acc[ms][ns] = (f32x16){};

  gemm256_mainloop(A + (size_t)bm * 256 * 2048, Bt + (size_t)bn * 256 * 2048, 2048, tid, smem, acc);

  int wid = tid >> 6, lane = tid & 63;
  int wr = wid >> 2, wc = wid & 3;
  int l31 = lane & 31, hi = lane >> 5;
#pragma unroll
  for (int ns = 0; ns < 2; ++ns) {
    int col = bn * 256 + wc * 64 + ns * 32 + l31;
    float bv = bias[col];
#pragma unroll
    for (int ms = 0; ms < 4; ++ms) {
#pragma unroll
      for (int reg = 0; reg < 16; ++reg) {
        int row = bm * 256 + wr * 128 + ms * 32 + (reg & 3) + 8 * (reg >> 2) + 4 * hi;
        out[(size_t)row * 2048 + col] = acc[ms][ns][reg] + bv;
      }
    }
  }
}

// ---------------- Flash attention: QBLK=256 (8 waves x 32 rows), paired q-tiles, dbuf K/V ----------------
// Grid is (bh, pairi) with bh = blockIdx.x: the 4 blocks sharing one (b,h)'s K/V land on
// the SAME XCD (64 % 8 == 0) -> K/V reads are L2-resident (~8 bh x 512KB = 4MB per XCD).
__global__ __launch_bounds__(512) void attn_kernel(const unsigned short* __restrict__ qb,
                                                   const unsigned short* __restrict__ kb,
                                                   const unsigned short* __restrict__ vtb,
                                                   unsigned short* __restrict__ ob) {
  extern __shared__ char asmem[];
  int bh = blockIdx.x;     // 0..63
  int pairi = blockIdx.y;  // 0..3
  int b = bh >> 4, h = bh & 15;
  int tid = threadIdx.x, wid = tid >> 6, lane = tid & 63;
  int l31 = lane & 31, hi = lane >> 5;

  const unsigned short* Q  = qb  + (size_t)bh * 2048 * 128;
  const unsigned short* K  = kb  + (size_t)bh * 2048 * 128;
  const unsigned short* Vt = vtb + (size_t)bh * 128 * 2048;

#pragma unroll 1
  for (int pass = 0; pass < 2; ++pass) {
    int qt = pass == 0 ? (7 - pairi) : pairi;   // 256-row q-tile
    int NT = 4 * qt + 4;
    int qbase = qt * 256 + wid * 32;
    int qrow = qbase + l31;

    short8 qf[8];
#pragma unroll
    for (int kc = 0; kc < 8; ++kc)
      qf[kc] = *(const short8*)(Q + (size_t)qrow * 128 + kc * 16 + hi * 8);

    f32x16 o0 = {}, o1 = {}, o2 = {}, o3 = {};  // O^T[d][q=l31]
    float m_run = -1e30f, l_run = 0.f;

    // prologue: stage tile 0 into buf0 (512 threads: 2 iters per matrix)
    {
      char* kb_ = asmem;
#pragma unroll
      for (int it = 0; it < 2; ++it) {
        int li = it * 512 + tid;
        int r = li >> 4, c = li & 15;
        GLOAD16(K + (size_t)r * 128 + (c ^ (r & 7)) * 8, kb_ + li * 16);
      }
#pragma unroll
      for (int it = 0; it < 2; ++it) {
        int li = it * 512 + tid;
        int r = li >> 3, c = li & 7;
        GLOAD16(Vt + (size_t)r * 2048 + (c ^ (r & 7)) * 8, kb_ + 16384 + li * 16);
      }
    }
    VMCNT0();
    BAR();

#pragma unroll 1
    for (int kt = 0; kt < NT; ++kt) {
      char* cb = asmem + ((kt & 1) << 15);
      // stage next tile into the other buffer (hidden under this tile's compute)
      if (kt + 1 < NT) {
        char* nb = asmem + (((kt + 1) & 1) << 15);
        int kt1 = kt + 1;
#pragma unroll
        for (int it = 0; it < 2; ++it) {
          int li = it * 512 + tid;
          int r = li >> 4, c = li & 15;
          GLOAD16(K + (size_t)(kt1 * 64 + r) * 128 + (c ^ (r & 7)) * 8, nb + li * 16);
        }
#pragma unroll
        for (int it = 0; it < 2; ++it) {
          int li = it * 512 + tid;
          int r = li >> 3, c = li & 7;
          GLOAD16(Vt + (size_t)r * 2048 + kt1 * 64 + (c ^ (r & 7)) * 8, nb + 16384 + li * 16);
        }
      }

      bool active = (kt * 64 <= qbase + 31);  // wave-uniform
      if (active) {
        const char* k_l = cb;
        const char* v_l = cb + 16384;

        f32x16 s0v = {}, s1v = {};
        PRIO(1);
#pragma unroll
        for (int kc = 0; kc < 8; ++kc) {
          int cg = kc * 2 + hi;
          int sw = l31 & 7;
          short8 kf0 = *(const short8*)(k_l + l31 * 256 + ((cg ^ sw) * 16));
          s0v = __builtin_amdgcn_mfma_f32_32x32x16_bf16(kf0, qf[kc], s0v, 0, 0, 0);
          short8 kf1 = *(const short8*)(k_l + (32 + l31) * 256 + ((cg ^ sw) * 16));
          s1v = __builtin_amdgcn_mfma_f32_32x32x16_bf16(kf1, qf[kc], s1v, 0, 0, 0);
        }
        PRIO(0);

        if (kt * 64 + 63 > qbase) {
          int kvb = kt * 64 + 4 * hi;
#pragma unroll
          for (int r = 0; r < 16; ++r) {
            int kv = kvb + (r & 3) + 8 * (r >> 2);
            if (kv > qrow) s0v[r] = -1e30f;
            if (kv + 32 > qrow) s1v[r] = -1e30f;
          }
        }

        float tmax[16];
#pragma unroll
        for (int i = 0; i < 16; ++i) tmax[i] = fmaxf(s0v[i], s1v[i]);
#pragma unroll
        for (int st = 8; st >= 1; st >>= 1)
#pragma unroll
          for (int i = 0; i < st; ++i) tmax[i] = fmaxf(tmax[i], tmax[i + st]);
        float pmax = fmaxf(tmax[0], __shfl_xor(tmax[0], 32));

        if (!__all(pmax <= m_run + 8.0f)) {
          float mn = fmaxf(m_run, pmax);
          float alpha = exp2f(m_run - mn);
          m_run = mn; l_run *= alpha;
          o0 *= alpha; o1 *= alpha; o2 *= alpha; o3 *= alpha;
        }

#pragma unroll
        for (int i = 0; i < 16; ++i) {
          s0v[i] = exp2f(s0v[i] - m_run);
          s1v[i] = exp2f(s1v[i] - m_run);
        }
        float tsum[16];
#pragma unroll
        for (int i = 0; i < 16; ++i) tsum[i] = s0v[i] + s1v[i];
#pragma unroll
        for (int st = 8; st >= 1; st >>= 1)
#pragma unroll
          for (int i = 0; i < st; ++i) tsum[i] += tsum[i + st];
        float rsum = tsum[0] + __shfl_xor(tsum[0], 32);
        l_run += rsum;

#define BUILD_PA(sv, base, out)                                                \
        {                                                                      \
          unsigned int a_ = cvtpk(sv[base + 0], sv[base + 1]);                 \
          unsigned int c_ = cvtpk(sv[base + 2], sv[base + 3]);                 \
          unsigned int b_ = cvtpk(sv[base + 4], sv[base + 5]);                 \
          unsigned int d_ = cvtpk(sv[base + 6], sv[base + 7]);                 \
          uint2v r0_ = __builtin_amdgcn_permlane32_swap(a_, b_, false, false); \
          uint2v r1_ = __builtin_amdgcn_permlane32_swap(c_, d_, false, false); \
          union { unsigned int u[4]; short8 v; } uu_;                          \
          uu_.u[0] = r0_[0]; uu_.u[1] = r1_[0]; uu_.u[2] = r0_[1]; uu_.u[3] = r1_[1]; \
          out = uu_.v;                                                         \
        }
        short8 pa0, pa1, pa2, pa3;
        BUILD_PA(s0v, 0, pa0);
        BUILD_PA(s0v, 8, pa1);
        BUILD_PA(s1v, 0, pa2);
        BUILD_PA(s1v, 8, pa3);
#undef BUILD_PA

        PRIO(1);
#define PV_STEP(ovar, dt)                                                          \
        {                                                                          \
          int rv_ = dt * 32 + l31;                                                 \
          const char* vb_ = v_l + rv_ * 128;                                       \
          int sw_ = rv_ & 7;                                                       \
          short8 v0_ = *(const short8*)(vb_ + (((0 + hi) ^ sw_) * 16));            \
          ovar = __builtin_amdgcn_mfma_f32_32x32x16_bf16(v0_, pa0, ovar, 0, 0, 0); \
          short8 v1_ = *(const short8*)(vb_ + (((2 + hi) ^ sw_) * 16));            \
          ovar = __builtin_amdgcn_mfma_f32_32x32x16_bf16(v1_, pa1, ovar, 0, 0, 0); \
          short8 v2_ = *(const short8*)(vb_ + (((4 + hi) ^ sw_) * 16));            \
          ovar = __builtin_amdgcn_mfma_f32_32x32x16_bf16(v2_, pa2, ovar, 0, 0, 0); \
          short8 v3_ = *(const short8*)(vb_ + (((6 + hi) ^ sw_) * 16));            \
          ovar = __builtin_amdgcn_mfma_f32_32x32x16_bf16(v3_, pa3, ovar, 0, 0, 0); \
        }
        PV_STEP(o0, 0)
        PV_STEP(o1, 1)
        PV_STEP(o2, 2)
        PV_STEP(o3, 3)
#undef PV_STEP
        PRIO(0);
      }

      VMCNT0();  // next tile's stage complete (issued ~1 compute-phase ago)
      BAR();
    }

    float inv = 1.0f / l_run;
    size_t orow = (size_t)(b * 2048 + qt * 256 + wid * 32 + l31);
    unsigned short* ob_p = ob + orow * 2048 + h * 128;
#define STORE_DT(ovar, dt)                                                         \
    {                                                                              \
      _Pragma("unroll")                                                            \
      for (int rq = 0; rq < 4; ++rq) {                                             \
        unsigned int w0 = cvtpk(ovar[rq * 4 + 0] * inv, ovar[rq * 4 + 1] * inv);   \
        unsigned int w1 = cvtpk(ovar[rq * 4 + 2] * inv, ovar[rq * 4 + 3] * inv);   \
        uint2v st = {w0, w1};                                                      \
        *(uint2v*)(ob_p + dt * 32 + rq * 8 + 4 * hi) = st;                         \
      }                                                                            \
    }
    STORE_DT(o0, 0)
    STORE_DT(o1, 1)
    STORE_DT(o2, 2)
    STORE_DT(o3, 3)
#undef STORE_DT
  }
}

// ---------------- launch ----------------
extern "C" void kernel_launch(void* const* d_in, const int* in_sizes, int n_in,
                              void* d_out, int out_size, void* d_ws, size_t ws_size,
                              hipStream_t stream) {
  const float* x     = (const float*)d_in[0];
  const float* Wqkv  = (const float*)d_in[1];
  const float* bqkv  = (const float*)d_in[2];
  const float* Wproj = (const float*)d_in[3];
  const float* bproj = (const float*)d_in[4];
  float* out = (float*)d_out;

  char* ws = (char*)d_ws;
  unsigned short* x_bf   = (unsigned short*)ws;                         // 32MB, reused as attn_out
  unsigned short* wqkvt  = (unsigned short*)(ws + 33554432);            // 24MB
  unsigned short* wprojt = (unsigned short*)(ws + 33554432 + 25165824); // 8MB
  unsigned short* qb     = (unsigned short*)(ws + 67108864);            // 32MB (pre-scaled)
  unsigned short* kb     = (unsigned short*)(ws + 100663296);           // 32MB
  unsigned short* vtb    = (unsigned short*)(ws + 134217728);           // 32MB [bh][d][t]

  (void)hipFuncSetAttribute((const void*)gemm_qkv256_kernel,
                            hipFuncAttributeMaxDynamicSharedMemorySize, 131072);
  (void)hipFuncSetAttribute((const void*)gemm_proj256_kernel,
                            hipFuncAttributeMaxDynamicSharedMemorySize, 131072);
  (void)hipFuncSetAttribute((const void*)attn_kernel,
                            hipFuncAttributeMaxDynamicSharedMemorySize, 65536);

  cast_bf16_kernel<<<16384, 256, 0, stream>>>(x, x_bf);
  transpose_cast_kernel<<<dim3(192, 64), dim3(32, 8), 0, stream>>>(Wqkv, wqkvt, 2048, 6144);
  transpose_cast_kernel<<<dim3(64, 64), dim3(32, 8), 0, stream>>>(Wproj, wprojt, 2048, 2048);
  gemm_qkv256_kernel<<<768, 512, 131072, stream>>>(x_bf, wqkvt, bqkv, qb, kb, vtb);
  attn_kernel<<<dim3(64, 4), 512, 65536, stream>>>(qb, kb, vtb, x_bf /* attn_out */);
  gemm_proj256_kernel<<<256, 512, 131072, stream>>>(x_bf, wprojt, bproj, out);
}

// Round 15
// 393.520 us; speedup vs baseline: 1.1228x; 1.1228x over previous
//
#include <hip/hip_runtime.h>
#include <hip/hip_bf16.h>
#include <stdint.h>

typedef __attribute__((ext_vector_type(8))) short short8;
typedef __attribute__((ext_vector_type(4))) float f32x4;
typedef __attribute__((ext_vector_type(16))) float f32x16;
typedef __attribute__((ext_vector_type(2))) unsigned int uint2v;

__device__ __forceinline__ unsigned short f2bf(float f) {
  union { float f; unsigned int u; } v; v.f = f;
  unsigned int r = v.u + 0x7FFFu + ((v.u >> 16) & 1u);
  return (unsigned short)(r >> 16);
}

__device__ __forceinline__ unsigned int cvtpk(float lo, float hi) {
  unsigned int r;
  asm("v_cvt_pk_bf16_f32 %0, %1, %2" : "=v"(r) : "v"(lo), "v"(hi));
  return r;
}

#define GLOAD16(gsrc, ldst)                                                                  \
  __builtin_amdgcn_global_load_lds((const __attribute__((address_space(1))) void*)(gsrc),    \
                                   (__attribute__((address_space(3))) void*)(ldst), 16, 0, 0)

#define BAR() __builtin_amdgcn_s_barrier()
#define LGKMC(n) do { asm volatile("s_waitcnt lgkmcnt(" #n ")" ::: "memory"); \
                      __builtin_amdgcn_sched_barrier(0); } while (0)
#define LGKM0() LGKMC(0)
#define VMCNT0() asm volatile("s_waitcnt vmcnt(0)" ::: "memory")
#define VMCNT8() do { asm volatile("s_waitcnt vmcnt(8)" ::: "memory"); \
                      __builtin_amdgcn_sched_barrier(0); } while (0)
#define PRIO(x) __builtin_amdgcn_s_setprio(x)
#define MFMA16(d, a, b) d = __builtin_amdgcn_mfma_f32_16x16x32_bf16(a, b, d, 0, 0, 0)

// ---------------- cast x (fp32 -> bf16), 4 elems/thread ----------------
__global__ __launch_bounds__(256) void cast_bf16_kernel(const float* __restrict__ in,
                                                        unsigned short* __restrict__ out) {
  int i = blockIdx.x * 256 + threadIdx.x;
  float4 v = ((const float4*)in)[i];
  ushort4 o;
  o.x = f2bf(v.x); o.y = f2bf(v.y); o.z = f2bf(v.z); o.w = f2bf(v.w);
  ((ushort4*)out)[i] = o;
}

// ---------------- transpose + cast W: [K][N] fp32 -> [N][K] bf16 ----------------
__global__ __launch_bounds__(256) void transpose_cast_kernel(const float* __restrict__ W,
                                                             unsigned short* __restrict__ Wt,
                                                             int K, int N) {
  __shared__ float tile[32][33];
  int n0 = blockIdx.x * 32, k0 = blockIdx.y * 32;
  int tx = threadIdx.x, ty = threadIdx.y;
#pragma unroll
  for (int j = 0; j < 32; j += 8)
    tile[ty + j][tx] = W[(size_t)(k0 + ty + j) * N + n0 + tx];
  __syncthreads();
#pragma unroll
  for (int j = 0; j < 32; j += 8)
    Wt[(size_t)(n0 + ty + j) * K + k0 + tx] = f2bf(tile[tx][ty + j]);
}

// ---------------- 256x256 GEMM mainloop: clustered reads + counted lgkm consume ----------------
// (round-11/13 best-measured variant, 16x16x32 MFMA)
__device__ __forceinline__ void stage_half(const unsigned short* __restrict__ gp, int K,
                                           int kt, int half, char* lds_mat, int tid) {
#pragma unroll
  for (int it = 0; it < 2; ++it) {
    int li = half * 1024 + it * 512 + tid;  // 16B-chunk index in 256x64 tile
    int r = li >> 3, c = li & 7;
    int cs = c ^ (r & 7);
    GLOAD16(gp + (size_t)r * K + kt * 64 + cs * 8, lds_mat + li * 16);
  }
}

__device__ __forceinline__ void gemm256_mainloop(const unsigned short* __restrict__ Ap,
                                                 const unsigned short* __restrict__ Bp,
                                                 int K, int tid, char* smem,
                                                 f32x4 acc[8][4]) {
  char* sa = smem;           // A: 2 bufs x 32768 B
  char* sb = smem + 65536;   // B: 2 bufs x 32768 B
  const int KT = K >> 6;     // 32

  int wid = tid >> 6, lane = tid & 63;
  int wr = wid >> 2, wc = wid & 3;
  int lg = lane >> 4, l15 = lane & 15;
  int swz7 = l15 & 7;

#define LDA(ab, m, kc) \
  (*(const short8*)((const unsigned short*)(ab) + (size_t)((wr * 128 + (m) * 16 + l15) * 64 + ((((kc) * 4 + lg) ^ swz7) * 8))))
#define LDB(bb, n, kc) \
  (*(const short8*)((const unsigned short*)(bb) + (size_t)((wc * 64 + (n) * 16 + l15) * 64 + ((((kc) * 4 + lg) ^ swz7) * 8))))

  // prologue: t0 fully (oldest 8 loads), then t1 fully (next 8, stay in flight)
  stage_half(Bp, K, 0, 0, sb, tid);
  stage_half(Bp, K, 0, 1, sb, tid);
  stage_half(Ap, K, 0, 0, sa, tid);
  stage_half(Ap, K, 0, 1, sa, tid);
  stage_half(Bp, K, 1, 0, sb + 32768, tid);
  stage_half(Bp, K, 1, 1, sb + 32768, tid);
  stage_half(Ap, K, 1, 0, sa + 32768, tid);
  stage_half(Ap, K, 1, 1, sa + 32768, tid);
  VMCNT8();  // t0's 8 loads complete; t1's 8 float
  BAR();

  for (int t = 0; t < KT; ++t) {
    int p = t & 1;
    const char* ab = sa + p * 32768;
    const char* bb = sb + p * 32768;
    int kt2 = (t + 2 < KT) ? t + 2 : KT - 1;

    short8 bq01[2][2], bq23[2][2], aq[4][2], aq2[4][2];
    // ---- issue all 24 ds_reads in order: bq01(4), aq03(8), bq23(4), aq47(8) ----
#pragma unroll
    for (int n = 0; n < 2; ++n) { bq01[n][0] = LDB(bb, n, 0); bq01[n][1] = LDB(bb, n, 1); }
#pragma unroll
    for (int m = 0; m < 4; ++m) { aq[m][0] = LDA(ab, m, 0); aq[m][1] = LDA(ab, m, 1); }
#pragma unroll
    for (int n = 0; n < 2; ++n) { bq23[n][0] = LDB(bb, n + 2, 0); bq23[n][1] = LDB(bb, n + 2, 1); }
#pragma unroll
    for (int m = 0; m < 4; ++m) { aq2[m][0] = LDA(ab, m + 4, 0); aq2[m][1] = LDA(ab, m + 4, 1); }

    // ---- Q1 = m0-3 x n0-1 (needs oldest 12) ----
    LGKMC(12);
    PRIO(1);
#pragma unroll
    for (int kc = 0; kc < 2; ++kc)
#pragma unroll
      for (int m = 0; m < 4; ++m)
#pragma unroll
        for (int n = 0; n < 2; ++n)
          MFMA16(acc[m][n], aq[m][kc], bq01[n][kc]);
    PRIO(0);

    // ---- bq23 done -> all B reads of tile t complete; BAR; stage B(t+2)->p ----
    LGKMC(8);
    BAR();
    stage_half(Bp, K, kt2, 0, sb + p * 32768, tid);
    stage_half(Bp, K, kt2, 1, sb + p * 32768, tid);

    // ---- Q2 = m0-3 x n2-3 ----
    PRIO(1);
#pragma unroll
    for (int kc = 0; kc < 2; ++kc)
#pragma unroll
      for (int m = 0; m < 4; ++m)
#pragma unroll
        for (int n = 0; n < 2; ++n)
          MFMA16(acc[m][n + 2], aq[m][kc], bq23[n][kc]);
    PRIO(0);

    // ---- aq47 done -> Q3 = m4-7 x n2-3 ----
    LGKMC(0);
    PRIO(1);
#pragma unroll
    for (int kc = 0; kc < 2; ++kc)
#pragma unroll
      for (int m = 0; m < 4; ++m)
#pragma unroll
        for (int n = 0; n < 2; ++n)
          MFMA16(acc[m + 4][n + 2], aq2[m][kc], bq23[n][kc]);
    PRIO(0);

    // ---- all A reads complete; BAR; stage A(t+2)->p; Q4 = m4-7 x n0-1 ----
    BAR();
    stage_half(Ap, K, kt2, 0, sa + p * 32768, tid);
    stage_half(Ap, K, kt2, 1, sa + p * 32768, tid);
    PRIO(1);
#pragma unroll
    for (int kc = 0; kc < 2; ++kc)
#pragma unroll
      for (int m = 0; m < 4; ++m)
#pragma unroll
        for (int n = 0; n < 2; ++n)
          MFMA16(acc[m + 4][n], aq2[m][kc], bq01[n][kc]);
    PRIO(0);
    VMCNT8();  // A(t+1),B(t+1) complete; A(t+2),B(t+2) (8 loads) float
    BAR();
  }
#undef LDA
#undef LDB
}

// ---------------- QKV GEMM 256^2: chunked XCD map; q/k + v^T all via LDS for coalesced stores ----------------
__global__ __launch_bounds__(512, 2) void gemm_qkv256_kernel(const unsigned short* __restrict__ A,
                                                             const unsigned short* __restrict__ Bt,
                                                             const float* __restrict__ bias,
                                                             unsigned short* __restrict__ qb,
                                                             unsigned short* __restrict__ kb,
                                                             unsigned short* __restrict__ vtb) {
  extern __shared__ char smem[];
  int wg = blockIdx.x;                 // 768 blocks
  int xcd = wg & 7, idx = wg >> 3;     // 96 per XCD
  int bn = xcd * 3 + idx % 3;          // bn-fast: 3 concurrent blocks share each A-panel in L2
  int bm = idx / 3;                    // 0..31
  int tid = threadIdx.x;

  f32x4 acc[8][4];
  f32x4 zero = {0.f, 0.f, 0.f, 0.f};
#pragma unroll
  for (int m = 0; m < 8; ++m)
#pragma unroll
    for (int n = 0; n < 4; ++n) acc[m][n] = zero;

  gemm256_mainloop(A + (size_t)bm * 256 * 2048, Bt + (size_t)bn * 256 * 2048, 2048, tid, smem, acc);

  const float QSCALE = (float)(0.08838834764831845 * 1.4426950408889634);  // D^-0.5 * log2(e)
  int wid = tid >> 6, lane = tid & 63;
  int wr = wid >> 2, wc = wid & 3, lg = lane >> 4, l15 = lane & 15;
  int l31 = lane & 31, hi = lane >> 5;

  if (bn >= 16) {
    // ---- v-block: transpose 256x256 tile via LDS, write [bh][d][t] coalesced ----
    VMCNT0();  // drain tail junk prefetches before reusing LDS
    BAR();
#pragma unroll
    for (int n = 0; n < 4; ++n) {
      int cl = wc * 64 + n * 16 + l15;
      float bv = bias[bn * 256 + cl];
#pragma unroll
      for (int m = 0; m < 8; ++m) {
        int rl = wr * 128 + m * 16 + lg * 4;
        unsigned int w0 = cvtpk(acc[m][n][0] + bv, acc[m][n][1] + bv);
        unsigned int w1 = cvtpk(acc[m][n][2] + bv, acc[m][n][3] + bv);
        uint2v pk = {w0, w1};
        *(uint2v*)(smem + cl * 512 + ((rl * 2) ^ ((cl & 7) << 4))) = pk;
      }
    }
    LGKM0();
    BAR();
    int t0_abs = bm * 256;
    int bq_ = t0_abs >> 11, t0 = t0_abs & 2047;
    int h0 = (bn * 256 - 4096) >> 7;  // first of 2 heads in this block
#pragma unroll
    for (int i = 0; i < 16; ++i) {
      int dloc = i * 16 + wid * 2 + hi;  // 0..255
      short8 vrow = *(const short8*)(smem + dloc * 512 + ((l31 * 16) ^ ((dloc & 7) << 4)));
      int bh_ = bq_ * 16 + h0 + (dloc >> 7);
      int d = dloc & 127;
      *(short8*)(vtb + ((size_t)bh_ * 128 + d) * 2048 + t0 + l31 * 8) = vrow;
    }
  } else {
    // ---- q/k block: LDS round-trip for coalesced [bh][t][d] stores ----
    // Write row-major bf16 [row 0..255][col 0..255] with byte-XOR ((row&15)<<4);
    // read short8 rows -> 16B stores, 256B-contiguous per (t, head).
    VMCNT0();  // drain tail junk prefetches before reusing LDS
    BAR();
    bool isq = (bn < 8);
#pragma unroll
    for (int n = 0; n < 4; ++n) {
      int cl = wc * 64 + n * 16 + l15;
      float bv = bias[bn * 256 + cl];
#pragma unroll
      for (int m = 0; m < 8; ++m) {
#pragma unroll
        for (int g = 0; g < 4; ++g) {
          int rl = wr * 128 + m * 16 + lg * 4 + g;
          float r = acc[m][n][g] + bv;
          if (isq) r *= QSCALE;
          *(unsigned short*)(smem + rl * 512 + ((cl * 2) ^ ((rl & 15) << 4))) = f2bf(r);
        }
      }
    }
    LGKM0();
    BAR();
    int t0_abs = bm * 256;
    unsigned short* dst = isq ? qb : kb;
    int h0 = ((bn & 7) * 256) >> 7;  // first of 2 heads in this block
#pragma unroll
    for (int i = 0; i < 16; ++i) {
      int id = i * 512 + tid;          // 0..8191 chunk index
      int rl = id >> 5, c8 = id & 31;  // row 0..255, 16B-chunk 0..31
      short8 v = *(const short8*)(smem + rl * 512 + ((c8 * 16) ^ ((rl & 15) << 4)));
      int row = t0_abs + rl;
      int b = row >> 11, t = row & 2047;
      int h = h0 + (c8 >> 4);
      int d0 = (c8 & 15) * 8;
      *(short8*)(dst + ((size_t)(b * 16 + h) * 2048 + t) * 128 + d0) = v;
    }
  }
}

// ---------------- Proj GEMM 256^2: fp32 output + bias ----------------
__global__ __launch_bounds__(512, 2) void gemm_proj256_kernel(const unsigned short* __restrict__ A,
                                                              const unsigned short* __restrict__ Bt,
                                                              const float* __restrict__ bias,
                                                              float* __restrict__ out) {
  extern __shared__ char smem[];
  int wg = blockIdx.x;
  int bm = wg >> 3, bn = wg & 7;  // one bn column per XCD; B-panel L2-resident
  int tid = threadIdx.x;

  f32x4 acc[8][4];
  f32x4 zero = {0.f, 0.f, 0.f, 0.f};
#pragma unroll
  for (int m = 0; m < 8; ++m)
#pragma unroll
    for (int n = 0; n < 4; ++n) acc[m][n] = zero;

  gemm256_mainloop(A + (size_t)bm * 256 * 2048, Bt + (size_t)bn * 256 * 2048, 2048, tid, smem, acc);

  int wid = tid >> 6, lane = tid & 63;
  int wr = wid >> 2, wc = wid & 3, lg = lane >> 4, l15 = lane & 15;
#pragma unroll
  for (int n = 0; n < 4; ++n) {
    int col = bn * 256 + wc * 64 + n * 16 + l15;
    float bv = bias[col];
#pragma unroll
    for (int m = 0; m < 8; ++m) {
#pragma unroll
      for (int g = 0; g < 4; ++g) {
        int row = bm * 256 + wr * 128 + m * 16 + lg * 4 + g;
        out[(size_t)row * 2048 + col] = acc[m][n][g] + bv;
      }
    }
  }
}

// ---------------- Flash attention: QBLK=256 (8 waves x 32 rows), paired q-tiles, dbuf K/V ----------------
// Grid is (bh, pairi) with bh = blockIdx.x: the 4 blocks sharing one (b,h)'s K/V land on
// the SAME XCD (64 % 8 == 0) -> K/V reads are L2-resident.
__global__ __launch_bounds__(512) void attn_kernel(const unsigned short* __restrict__ qb,
                                                   const unsigned short* __restrict__ kb,
                                                   const unsigned short* __restrict__ vtb,
                                                   unsigned short* __restrict__ ob) {
  extern __shared__ char asmem[];
  int bh = blockIdx.x;     // 0..63
  int pairi = blockIdx.y;  // 0..3
  int b = bh >> 4, h = bh & 15;
  int tid = threadIdx.x, wid = tid >> 6, lane = tid & 63;
  int l31 = lane & 31, hi = lane >> 5;

  const unsigned short* Q  = qb  + (size_t)bh * 2048 * 128;
  const unsigned short* K  = kb  + (size_t)bh * 2048 * 128;
  const unsigned short* Vt = vtb + (size_t)bh * 128 * 2048;

#pragma unroll 1
  for (int pass = 0; pass < 2; ++pass) {
    int qt = pass == 0 ? (7 - pairi) : pairi;   // 256-row q-tile
    int NT = 4 * qt + 4;
    int qbase = qt * 256 + wid * 32;
    int qrow = qbase + l31;

    short8 qf[8];
#pragma unroll
    for (int kc = 0; kc < 8; ++kc)
      qf[kc] = *(const short8*)(Q + (size_t)qrow * 128 + kc * 16 + hi * 8);

    f32x16 o0 = {}, o1 = {}, o2 = {}, o3 = {};  // O^T[d][q=l31]
    float m_run = -1e30f, l_run = 0.f;

    // prologue: stage tile 0 into buf0 (512 threads: 2 iters per matrix)
    {
      char* kb_ = asmem;
#pragma unroll
      for (int it = 0; it < 2; ++it) {
        int li = it * 512 + tid;
        int r = li >> 4, c = li & 15;
        GLOAD16(K + (size_t)r * 128 + (c ^ (r & 7)) * 8, kb_ + li * 16);
      }
#pragma unroll
      for (int it = 0; it < 2; ++it) {
        int li = it * 512 + tid;
        int r = li >> 3, c = li & 7;
        GLOAD16(Vt + (size_t)r * 2048 + (c ^ (r & 7)) * 8, kb_ + 16384 + li * 16);
      }
    }
    VMCNT0();
    BAR();

#pragma unroll 1
    for (int kt = 0; kt < NT; ++kt) {
      char* cb = asmem + ((kt & 1) << 15);
      // stage next tile into the other buffer (hidden under this tile's compute)
      if (kt + 1 < NT) {
        char* nb = asmem + (((kt + 1) & 1) << 15);
        int kt1 = kt + 1;
#pragma unroll
        for (int it = 0; it < 2; ++it) {
          int li = it * 512 + tid;
          int r = li >> 4, c = li & 15;
          GLOAD16(K + (size_t)(kt1 * 64 + r) * 128 + (c ^ (r & 7)) * 8, nb + li * 16);
        }
#pragma unroll
        for (int it = 0; it < 2; ++it) {
          int li = it * 512 + tid;
          int r = li >> 3, c = li & 7;
          GLOAD16(Vt + (size_t)r * 2048 + kt1 * 64 + (c ^ (r & 7)) * 8, nb + 16384 + li * 16);
        }
      }

      bool active = (kt * 64 <= qbase + 31);  // wave-uniform
      if (active) {
        const char* k_l = cb;
        const char* v_l = cb + 16384;

        f32x16 s0v = {}, s1v = {};
        PRIO(1);
#pragma unroll
        for (int kc = 0; kc < 8; ++kc) {
          int cg = kc * 2 + hi;
          int sw = l31 & 7;
          short8 kf0 = *(const short8*)(k_l + l31 * 256 + ((cg ^ sw) * 16));
          s0v = __builtin_amdgcn_mfma_f32_32x32x16_bf16(kf0, qf[kc], s0v, 0, 0, 0);
          short8 kf1 = *(const short8*)(k_l + (32 + l31) * 256 + ((cg ^ sw) * 16));
          s1v = __builtin_amdgcn_mfma_f32_32x32x16_bf16(kf1, qf[kc], s1v, 0, 0, 0);
        }
        PRIO(0);

        if (kt * 64 + 63 > qbase) {
          int kvb = kt * 64 + 4 * hi;
#pragma unroll
          for (int r = 0; r < 16; ++r) {
            int kv = kvb + (r & 3) + 8 * (r >> 2);
            if (kv > qrow) s0v[r] = -1e30f;
            if (kv + 32 > qrow) s1v[r] = -1e30f;
          }
        }

        float tmax[16];
#pragma unroll
        for (int i = 0; i < 16; ++i) tmax[i] = fmaxf(s0v[i], s1v[i]);
#pragma unroll
        for (int st = 8; st >= 1; st >>= 1)
#pragma unroll
          for (int i = 0; i < st; ++i) tmax[i] = fmaxf(tmax[i], tmax[i + st]);
        float pmax = fmaxf(tmax[0], __shfl_xor(tmax[0], 32));

        if (!__all(pmax <= m_run + 8.0f)) {
          float mn = fmaxf(m_run, pmax);
          float alpha = exp2f(m_run - mn);
          m_run = mn; l_run *= alpha;
          o0 *= alpha; o1 *= alpha; o2 *= alpha; o3 *= alpha;
        }

#pragma unroll
        for (int i = 0; i < 16; ++i) {
          s0v[i] = exp2f(s0v[i] - m_run);
          s1v[i] = exp2f(s1v[i] - m_run);
        }
        float tsum[16];
#pragma unroll
        for (int i = 0; i < 16; ++i) tsum[i] = s0v[i] + s1v[i];
#pragma unroll
        for (int st = 8; st >= 1; st >>= 1)
#pragma unroll
          for (int i = 0; i < st; ++i) tsum[i] += tsum[i + st];
        float rsum = tsum[0] + __shfl_xor(tsum[0], 32);
        l_run += rsum;

#define BUILD_PA(sv, base, out)                                                \
        {                                                                      \
          unsigned int a_ = cvtpk(sv[base + 0], sv[base + 1]);                 \
          unsigned int c_ = cvtpk(sv[base + 2], sv[base + 3]);                 \
          unsigned int b_ = cvtpk(sv[base + 4], sv[base + 5]);                 \
          unsigned int d_ = cvtpk(sv[base + 6], sv[base + 7]);                 \
          uint2v r0_ = __builtin_amdgcn_permlane32_swap(a_, b_, false, false); \
          uint2v r1_ = __builtin_amdgcn_permlane32_swap(c_, d_, false, false); \
          union { unsigned int u[4]; short8 v; } uu_;                          \
          uu_.u[0] = r0_[0]; uu_.u[1] = r1_[0]; uu_.u[2] = r0_[1]; uu_.u[3] = r1_[1]; \
          out = uu_.v;                                                         \
        }
        short8 pa0, pa1, pa2, pa3;
        BUILD_PA(s0v, 0, pa0);
        BUILD_PA(s0v, 8, pa1);
        BUILD_PA(s1v, 0, pa2);
        BUILD_PA(s1v, 8, pa3);
#undef BUILD_PA

        PRIO(1);
#define PV_STEP(ovar, dt)                                                          \
        {                                                                          \
          int rv_ = dt * 32 + l31;                                                 \
          const char* vb_ = v_l + rv_ * 128;                                       \
          int sw_ = rv_ & 7;                                                       \
          short8 v0_ = *(const short8*)(vb_ + (((0 + hi) ^ sw_) * 16));            \
          ovar = __builtin_amdgcn_mfma_f32_32x32x16_bf16(v0_, pa0, ovar, 0, 0, 0); \
          short8 v1_ = *(const short8*)(vb_ + (((2 + hi) ^ sw_) * 16));            \
          ovar = __builtin_amdgcn_mfma_f32_32x32x16_bf16(v1_, pa1, ovar, 0, 0, 0); \
          short8 v2_ = *(const short8*)(vb_ + (((4 + hi) ^ sw_) * 16));            \
          ovar = __builtin_amdgcn_mfma_f32_32x32x16_bf16(v2_, pa2, ovar, 0, 0, 0); \
          short8 v3_ = *(const short8*)(vb_ + (((6 + hi) ^ sw_) * 16));            \
          ovar = __builtin_amdgcn_mfma_f32_32x32x16_bf16(v3_, pa3, ovar, 0, 0, 0); \
        }
        PV_STEP(o0, 0)
        PV_STEP(o1, 1)
        PV_STEP(o2, 2)
        PV_STEP(o3, 3)
#undef PV_STEP
        PRIO(0);
      }

      VMCNT0();  // next tile's stage complete (issued ~1 compute-phase ago)
      BAR();
    }

    float inv = 1.0f / l_run;
    size_t orow = (size_t)(b * 2048 + qt * 256 + wid * 32 + l31);
    unsigned short* ob_p = ob + orow * 2048 + h * 128;
#define STORE_DT(ovar, dt)                                                         \
    {                                                                              \
      _Pragma("unroll")                                                            \
      for (int rq = 0; rq < 4; ++rq) {                                             \
        unsigned int w0 = cvtpk(ovar[rq * 4 + 0] * inv, ovar[rq * 4 + 1] * inv);   \
        unsigned int w1 = cvtpk(ovar[rq * 4 + 2] * inv, ovar[rq * 4 + 3] * inv);   \
        uint2v st = {w0, w1};                                                      \
        *(uint2v*)(ob_p + dt * 32 + rq * 8 + 4 * hi) = st;                         \
      }                                                                            \
    }
    STORE_DT(o0, 0)
    STORE_DT(o1, 1)
    STORE_DT(o2, 2)
    STORE_DT(o3, 3)
#undef STORE_DT
  }
}

// ---------------- launch ----------------
extern "C" void kernel_launch(void* const* d_in, const int* in_sizes, int n_in,
                              void* d_out, int out_size, void* d_ws, size_t ws_size,
                              hipStream_t stream) {
  const float* x     = (const float*)d_in[0];
  const float* Wqkv  = (const float*)d_in[1];
  const float* bqkv  = (const float*)d_in[2];
  const float* Wproj = (const float*)d_in[3];
  const float* bproj = (const float*)d_in[4];
  float* out = (float*)d_out;

  char* ws = (char*)d_ws;
  unsigned short* x_bf   = (unsigned short*)ws;                         // 32MB, reused as attn_out
  unsigned short* wqkvt  = (unsigned short*)(ws + 33554432);            // 24MB
  unsigned short* wprojt = (unsigned short*)(ws + 33554432 + 25165824); // 8MB
  unsigned short* qb     = (unsigned short*)(ws + 67108864);            // 32MB (pre-scaled)
  unsigned short* kb     = (unsigned short*)(ws + 100663296);           // 32MB
  unsigned short* vtb    = (unsigned short*)(ws + 134217728);           // 32MB [bh][d][t]

  (void)hipFuncSetAttribute((const void*)gemm_qkv256_kernel,
                            hipFuncAttributeMaxDynamicSharedMemorySize, 131072);
  (void)hipFuncSetAttribute((const void*)gemm_proj256_kernel,
                            hipFuncAttributeMaxDynamicSharedMemorySize, 131072);
  (void)hipFuncSetAttribute((const void*)attn_kernel,
                            hipFuncAttributeMaxDynamicSharedMemorySize, 65536);

  cast_bf16_kernel<<<16384, 256, 0, stream>>>(x, x_bf);
  transpose_cast_kernel<<<dim3(192, 64), dim3(32, 8), 0, stream>>>(Wqkv, wqkvt, 2048, 6144);
  transpose_cast_kernel<<<dim3(64, 64), dim3(32, 8), 0, stream>>>(Wproj, wprojt, 2048, 2048);
  gemm_qkv256_kernel<<<768, 512, 131072, stream>>>(x_bf, wqkvt, bqkv, qb, kb, vtb);
  attn_kernel<<<dim3(64, 4), 512, 65536, stream>>>(qb, kb, vtb, x_bf /* attn_out */);
  gemm_proj256_kernel<<<256, 512, 131072, stream>>>(x_bf, wprojt, bproj, out);
}